// Round 8
// baseline (97.427 us; speedup 1.0000x reference)
//
#include <hip/hip_runtime.h>
#include <cstdint>
#include <cstddef>

#define BB   32768
#define DD   8
#define LLV  16
#define TBL  524288
#define HID  512

typedef __attribute__((ext_vector_type(8))) short short8;
typedef __attribute__((ext_vector_type(8))) unsigned short u16x8;
typedef __attribute__((ext_vector_type(4))) float f32x4;
typedef __attribute__((ext_vector_type(2))) float f32x2;

// primes mod 2^32
__device__ __constant__ uint32_t PR[8] = {
    2654436881u, 1620619981u, 1500450271u, 3267000013u,
    1459886047u, 4093082899u,  986956175u, 3628273133u
};

__device__ __forceinline__ unsigned short f2bf(float f) {
    uint32_t u = __float_as_uint(f);
    uint32_t r = (u + 0x7fffu + ((u >> 16) & 1u)) >> 16;   // RNE
    return (unsigned short)r;
}
__device__ __forceinline__ float bf2f(unsigned short u) {
    return __uint_as_float(((uint32_t)u) << 16);
}

__device__ __forceinline__ void gload_lds16(const void* gsrc, void* ldst) {
    __builtin_amdgcn_global_load_lds(
        (const __attribute__((address_space(1))) unsigned int*)gsrc,
        (__attribute__((address_space(3))) unsigned int*)ldst,
        16, 0, 0);
}

// per-sample: cumsum -> sort -> 9 vertex hashes + weights
__device__ __forceinline__ void enc_idx(const float xs[8], float Kl,
                                        uint32_t idx9[9], float w9[9])
{
    float fr[8];
    int   base[8];
    float cs = 0.f;
#pragma unroll
    for (int i2 = 0; i2 < 8; i2++) {
        cs += xs[i2];                 // sequential fp32 cumsum (matches np)
        float p = cs * Kl;
        fr[i2]   = p - truncf(p);
        base[i2] = (int)floorf(p);
    }

    float c[8];
#pragma unroll
    for (int i2 = 0; i2 < 8; i2++) c[i2] = fr[i2];
#define CE(a_, b_) { float lo_ = fminf(c[a_], c[b_]); float hi_ = fmaxf(c[a_], c[b_]); c[a_] = lo_; c[b_] = hi_; }
    CE(0,1) CE(2,3) CE(4,5) CE(6,7)
    CE(0,2) CE(1,3) CE(4,6) CE(5,7)
    CE(1,2) CE(5,6) CE(0,4) CE(3,7)
    CE(1,5) CE(2,6)
    CE(1,4) CE(3,6)
    CE(2,4) CE(3,5)
    CE(3,4)
#undef CE

    float prevc = 0.f;
#pragma unroll
    for (int j = 0; j < 9; j++) {
        float cj = (j < 8) ? c[j] : 1.0f;
        uint32_t h = 0;
        int prev = 0;
#pragma unroll
        for (int i2 = 0; i2 < 8; i2++) {
            int ai = base[i2] + (fr[i2] >= cj ? 1 : 0);
            h ^= (uint32_t)(ai - prev) * PR[i2];
            prev = ai;
        }
        idx9[j] = h & (TBL - 1);
        w9[j]   = cj - prevc;
        prevc   = cj;
    }
}

// ---------------- encoding: level-major, asm-batched gathers ----------------
__global__ __launch_bounds__(256) void k_encode(
    const float* __restrict__ x, const float* __restrict__ T,
    const float* __restrict__ Karr, unsigned short* __restrict__ h0T)
{
    int i = blockIdx.x;
    int l = (i & 7) + ((i >> 10) << 3);
    int b = ((i & 1023) >> 3) * 256 + threadIdx.x;

    const float4 x0 = *(const float4*)(x + (size_t)b * DD);
    const float4 x1 = *(const float4*)(x + (size_t)b * DD + 4);
    float xs[8] = {x0.x, x0.y, x0.z, x0.w, x1.x, x1.y, x1.z, x1.w};

    float Kl = Karr[l];
    const f32x2* Tl = (const f32x2*)(T + ((size_t)l * TBL) * 2);

    uint32_t idx9[9];
    float    w9[9];
    enc_idx(xs, Kl, idx9, w9);

    f32x2 t0, t1, t2, t3, t4, t5, t6, t7, t8;
#define GL(n) asm volatile("global_load_dwordx2 %0, %1, off" \
                           : "=v"(t##n) : "v"(Tl + idx9[n]));
    GL(0) GL(1) GL(2) GL(3) GL(4) GL(5) GL(6) GL(7) GL(8)
#undef GL
    asm volatile("s_waitcnt vmcnt(0)"
        : "+v"(t0), "+v"(t1), "+v"(t2), "+v"(t3), "+v"(t4),
          "+v"(t5), "+v"(t6), "+v"(t7), "+v"(t8));
    __builtin_amdgcn_sched_barrier(0);

    float f0, f1;
    f0 = t0[0] * w9[0];  f1 = t0[1] * w9[0];
    f0 = fmaf(t1[0], w9[1], f0); f1 = fmaf(t1[1], w9[1], f1);
    f0 = fmaf(t2[0], w9[2], f0); f1 = fmaf(t2[1], w9[2], f1);
    f0 = fmaf(t3[0], w9[3], f0); f1 = fmaf(t3[1], w9[3], f1);
    f0 = fmaf(t4[0], w9[4], f0); f1 = fmaf(t4[1], w9[4], f1);
    f0 = fmaf(t5[0], w9[5], f0); f1 = fmaf(t5[1], w9[5], f1);
    f0 = fmaf(t6[0], w9[6], f0); f1 = fmaf(t6[1], w9[6], f1);
    f0 = fmaf(t7[0], w9[7], f0); f1 = fmaf(t7[1], w9[7], f1);
    f0 = fmaf(t8[0], w9[8], f0); f1 = fmaf(t8[1], w9[8], f1);
    f0 /= Kl;
    f1 /= Kl;

    h0T[(size_t)(l * 2 + 0) * BB + b] = f2bf(f0);
    h0T[(size_t)(l * 2 + 1) * BB + b] = f2bf(f1);
}

// ---------------- pack: planes + x -> row-major bf16 [B][64] (zero-padded K) ----
__global__ __launch_bounds__(256) void k_pack(
    const unsigned short* __restrict__ h0T, const float* __restrict__ x,
    unsigned short* __restrict__ h0b)
{
    int b = blockIdx.x * 256 + threadIdx.x;
    unsigned short row[64];
    const float4 x0 = *(const float4*)(x + (size_t)b * 8);
    const float4 x1 = *(const float4*)(x + (size_t)b * 8 + 4);
    row[0] = f2bf(x0.x); row[1] = f2bf(x0.y); row[2] = f2bf(x0.z); row[3] = f2bf(x0.w);
    row[4] = f2bf(x1.x); row[5] = f2bf(x1.y); row[6] = f2bf(x1.z); row[7] = f2bf(x1.w);
#pragma unroll
    for (int p = 0; p < 32; p++) row[8 + p] = h0T[(size_t)p * BB + b];
#pragma unroll
    for (int c = 40; c < 64; c++) row[c] = 0;
#pragma unroll
    for (int i = 0; i < 8; i++)
        *(u16x8*)(h0b + (size_t)b * 64 + i * 8) = *(u16x8*)(row + i * 8);
}

// ---------------- fused weight converts: w2 (256 blocks) + w1-pad (32 blocks) ----
__global__ __launch_bounds__(256) void k_cvtw(
    const float* __restrict__ w2, unsigned short* __restrict__ o2,
    const float* __restrict__ w1, unsigned short* __restrict__ o1)
{
    int bid = blockIdx.x;
    if (bid < 256) {
        int i = bid * 256 + threadIdx.x;
        float4 v = *(const float4*)(w2 + (size_t)i * 4);
        ushort4 r;
        r.x = f2bf(v.x); r.y = f2bf(v.y); r.z = f2bf(v.z); r.w = f2bf(v.w);
        *(ushort4*)(o2 + (size_t)i * 4) = r;
    } else {
        int i = (bid - 256) * 256 + threadIdx.x;   // 8192 threads
        int row = i >> 4, c4 = (i & 15) * 4;
        ushort4 r = make_ushort4(0, 0, 0, 0);
        if (c4 < 40) {
            float4 v = *(const float4*)(w1 + (size_t)row * 40 + c4);
            r.x = f2bf(v.x); r.y = f2bf(v.y); r.z = f2bf(v.z); r.w = f2bf(v.w);
        }
        *(ushort4*)(o1 + (size_t)row * 64 + c4) = r;
    }
}

// ------- unified bf16 MFMA GEMM, 2-phase dbuf, XCD-chunked swizzle -------
// grid = 1024 linear. pos = (bid&7)*128 + bid>>3 (bijective); row-block = pos>>2,
// col-block = pos&3: XCD x owns row-band [32x,32x+32) with col-chunks adjacent ->
// each A row-block is L2-resident for its 4 readers (live set ~2.5 MB < 4 MB L2).
template<int KK, int FUSE>
__global__ __launch_bounds__(256) void k_mgemm(
    const unsigned short* __restrict__ A, const unsigned short* __restrict__ Bw,
    const float* __restrict__ bias, unsigned short* __restrict__ Out,
    const float* __restrict__ aw, const float* __restrict__ vw,
    float* __restrict__ hpart)
{
    __shared__ unsigned short As[2][128 * 64];   // swizzled physical layout
    __shared__ unsigned short Bs[2][128 * 64];

    const int tid  = threadIdx.x;
    const int wid  = tid >> 6;
    const int lane = tid & 63;
    const int wm = wid >> 1, wn = wid & 1;
    const int lr = lane & 15;
    const int kg = lane >> 4;

    const int bid = blockIdx.x;
    const int pos = (bid & 7) * 128 + (bid >> 3);
    const int bx  = pos >> 2;       // row-block 0..255
    const int by  = pos & 3;        // col-block 0..3
    const int b0 = bx * 128;
    const int o0 = by * 128;

    f32x4 acc[4][4] = {};

    constexpr int NT = KK / 64;

#define STAGE(buf, k0)                                                          \
    {                                                                           \
        _Pragma("unroll")                                                       \
        for (int it = 0; it < 4; ++it) {                                        \
            int offb  = (it * 256 + tid) << 4;                                  \
            int loffb = offb ^ (((offb >> 7) & 7) << 4);                        \
            int row = loffb >> 7;                                               \
            int kel = (loffb & 127) >> 1;                                       \
            int ldsbyte = (buf) * 16384 + (((it * 256) + (wid * 64)) << 4);     \
            gload_lds16(A  + (size_t)(b0 + row) * KK + (k0) + kel,              \
                        (char*)As + ldsbyte);                                   \
            gload_lds16(Bw + (size_t)(o0 + row) * KK + (k0) + kel,              \
                        (char*)Bs + ldsbyte);                                   \
        }                                                                       \
    }

#define COMPUTE(buf)                                                            \
    {                                                                           \
        _Pragma("unroll")                                                       \
        for (int ks = 0; ks < 2; ++ks) {                                        \
            short8 af[4], bfr[4];                                               \
            int kbyte = ks * 64 + kg * 16;                                      \
            _Pragma("unroll")                                                   \
            for (int m = 0; m < 4; ++m) {                                       \
                int row = wm * 64 + m * 16 + lr;                                \
                int a = (buf) * 16384 + ((((row << 7) + kbyte)) ^ ((row & 7) << 4)); \
                af[m] = *(const short8*)((const char*)As + a);                  \
            }                                                                   \
            _Pragma("unroll")                                                   \
            for (int n = 0; n < 4; ++n) {                                       \
                int col = wn * 64 + n * 16 + lr;                                \
                int a = (buf) * 16384 + ((((col << 7) + kbyte)) ^ ((col & 7) << 4)); \
                bfr[n] = *(const short8*)((const char*)Bs + a);                 \
            }                                                                   \
            _Pragma("unroll")                                                   \
            for (int m = 0; m < 4; ++m)                                         \
                _Pragma("unroll")                                               \
                for (int n = 0; n < 4; ++n)                                     \
                    acc[m][n] = __builtin_amdgcn_mfma_f32_16x16x32_bf16(        \
                        af[m], bfr[n], acc[m][n], 0, 0, 0);                     \
        }                                                                       \
    }

    STAGE(0, 0)
    __syncthreads();                 // implicit vmcnt(0) drain before barrier
    int cur = 0;
#pragma unroll
    for (int t = 0; t < NT - 1; ++t) {
        STAGE(cur ^ 1, (t + 1) * 64)     // issue next tile's loads first
        COMPUTE(cur)                     // MFMA on current while loads fly
        __syncthreads();                 // drain + all waves done reading cur
        cur ^= 1;
    }
    COMPUTE(cur)
#undef STAGE
#undef COMPUTE

    float bo[4];
#pragma unroll
    for (int n = 0; n < 4; ++n) bo[n] = bias[o0 + wn * 64 + n * 16 + lr];

    if constexpr (FUSE) {
        // relu+bias in place (fp32)
#pragma unroll
        for (int m = 0; m < 4; ++m)
#pragma unroll
            for (int n = 0; n < 4; ++n)
#pragma unroll
                for (int r = 0; r < 4; ++r)
                    acc[m][n][r] = fmaxf(acc[m][n][r] + bo[n], 0.f);

        // head weights for this thread's 4 columns
        float hwv[5][4];
#pragma unroll
        for (int n = 0; n < 4; ++n) {
            int cg = o0 + wn * 64 + n * 16 + lr;
            hwv[0][n] = aw[cg];
            hwv[1][n] = aw[512 + cg];
            hwv[2][n] = aw[1024 + cg];
            hwv[3][n] = aw[1536 + cg];
            hwv[4][n] = vw[cg];
        }
        float* hp = hpart + (size_t)(by * 2 + wn) * (BB * 5);
#pragma unroll
        for (int hm = 0; hm < 5; ++hm) {
            f32x4 p[4];
#pragma unroll
            for (int m = 0; m < 4; ++m) {
                p[m] = acc[m][0] * hwv[hm][0];
                p[m] += acc[m][1] * hwv[hm][1];
                p[m] += acc[m][2] * hwv[hm][2];
                p[m] += acc[m][3] * hwv[hm][3];
            }
            // reduce over the 16 lr-lanes (kg preserved)
#pragma unroll
            for (int d = 1; d < 16; d <<= 1)
#pragma unroll
                for (int m = 0; m < 4; ++m)
#pragma unroll
                    for (int r = 0; r < 4; ++r)
                        p[m][r] += __shfl_xor(p[m][r], d);
            if (lr == 0) {
#pragma unroll
                for (int m = 0; m < 4; ++m)
#pragma unroll
                    for (int r = 0; r < 4; ++r)
                        hp[(size_t)(b0 + wm * 64 + m * 16 + kg * 4 + r) * 5 + hm] = p[m][r];
            }
        }
    } else {
        // bf16 store. C/D layout: col=lane&15, row=(lane>>4)*4+r
#pragma unroll
        for (int n = 0; n < 4; ++n) {
            int col = o0 + wn * 64 + n * 16 + lr;
#pragma unroll
            for (int m = 0; m < 4; ++m) {
                int rbase = b0 + wm * 64 + m * 16 + kg * 4;
#pragma unroll
                for (int r = 0; r < 4; ++r) {
                    float v = fmaxf(acc[m][n][r] + bo[n], 0.f);
                    Out[(size_t)(rbase + r) * HID + col] = f2bf(v);
                }
            }
        }
    }
}

// ---------------- reduce 8 head-partial slots + bias -> out ----------------
__global__ __launch_bounds__(256) void k_hreduce(
    const float* __restrict__ hpart, const float* __restrict__ ab,
    const float* __restrict__ vb, float* __restrict__ out)
{
    int i = blockIdx.x * 256 + threadIdx.x;    // 0 .. BB*5-1, = b*5+hm
    int b = i / 5;
    int hm = i - b * 5;
    float s = 0.f;
#pragma unroll
    for (int g = 0; g < 8; ++g) s += hpart[(size_t)g * (BB * 5) + i];
    s += (hm < 4) ? ab[hm] : vb[0];
    if (hm < 4) out[(size_t)b * 4 + hm] = s;
    else        out[(size_t)BB * 4 + b] = s;
}

extern "C" void kernel_launch(void* const* d_in, const int* in_sizes, int n_in,
                              void* d_out, int out_size, void* d_ws, size_t ws_size,
                              hipStream_t stream)
{
    const float* x    = (const float*)d_in[0];
    const float* T    = (const float*)d_in[1];
    const float* K    = (const float*)d_in[2];
    const float* l1w  = (const float*)d_in[3];
    const float* l1b  = (const float*)d_in[4];
    const float* l2w  = (const float*)d_in[5];
    const float* l2b  = (const float*)d_in[6];
    const float* actw = (const float*)d_in[7];
    const float* actb = (const float*)d_in[8];
    const float* valw = (const float*)d_in[9];
    const float* valb = (const float*)d_in[10];
    float* out = (float*)d_out;

    char* ws = (char*)d_ws;
    unsigned short* h0b   = (unsigned short*)ws;                   // B*64 bf16   = 4,194,304 B
    unsigned short* h1    = (unsigned short*)(ws + 4194304);       // B*512 bf16  = 33,554,432 B
    unsigned short* h0T   = (unsigned short*)(ws + 37748736);      // 32*B bf16   = 2,097,152 B
    unsigned short* w2b   = (unsigned short*)(ws + 39845888);      // 512*512 bf16= 524,288 B
    unsigned short* w1b   = (unsigned short*)(ws + 40370176);      // 512*64 bf16 = 65,536 B
    float*          hpart = (float*)(ws + 40435712);               // 8*B*5 f32   = 5,242,880 B

    k_encode        <<<2048, 256, 0, stream>>>(x, T, K, h0T);
    k_cvtw          <<<288, 256, 0, stream>>>(l2w, w2b, l1w, w1b);
    k_pack          <<<BB / 256, 256, 0, stream>>>(h0T, x, h0b);
    k_mgemm<64, 0>  <<<1024, 256, 0, stream>>>(h0b, w1b, l1b, h1,
                                               nullptr, nullptr, nullptr);
    k_mgemm<512, 1> <<<1024, 256, 0, stream>>>(h1, w2b, l2b, nullptr,
                                               actw, valw, hpart);
    k_hreduce       <<<BB * 5 / 256, 256, 0, stream>>>(hpart, actb, valb, out);
}

// Round 9
// 84.335 us; speedup vs baseline: 1.1552x; 1.1552x over previous
//
#include <hip/hip_runtime.h>
#include <cstdint>
#include <cstddef>

#define BB   32768
#define DD   8
#define LLV  16
#define TBL  524288
#define HID  512

typedef __attribute__((ext_vector_type(8))) short short8;
typedef __attribute__((ext_vector_type(8))) unsigned short u16x8;
typedef __attribute__((ext_vector_type(4))) float f32x4;
typedef __attribute__((ext_vector_type(2))) float f32x2;

// primes mod 2^32
__device__ __constant__ uint32_t PR[8] = {
    2654436881u, 1620619981u, 1500450271u, 3267000013u,
    1459886047u, 4093082899u,  986956175u, 3628273133u
};

__device__ __forceinline__ unsigned short f2bf(float f) {
    uint32_t u = __float_as_uint(f);
    uint32_t r = (u + 0x7fffu + ((u >> 16) & 1u)) >> 16;   // RNE
    return (unsigned short)r;
}

__device__ __forceinline__ void gload_lds16(const void* gsrc, void* ldst) {
    __builtin_amdgcn_global_load_lds(
        (const __attribute__((address_space(1))) unsigned int*)gsrc,
        (__attribute__((address_space(3))) unsigned int*)ldst,
        16, 0, 0);
}

// per-sample: cumsum -> sort -> 9 vertex hashes + weights
__device__ __forceinline__ void enc_idx(const float xs[8], float Kl,
                                        uint32_t idx9[9], float w9[9])
{
    float fr[8];
    int   base[8];
    float cs = 0.f;
#pragma unroll
    for (int i2 = 0; i2 < 8; i2++) {
        cs += xs[i2];                 // sequential fp32 cumsum (matches np)
        float p = cs * Kl;
        fr[i2]   = p - truncf(p);
        base[i2] = (int)floorf(p);
    }

    float c[8];
#pragma unroll
    for (int i2 = 0; i2 < 8; i2++) c[i2] = fr[i2];
#define CE(a_, b_) { float lo_ = fminf(c[a_], c[b_]); float hi_ = fmaxf(c[a_], c[b_]); c[a_] = lo_; c[b_] = hi_; }
    CE(0,1) CE(2,3) CE(4,5) CE(6,7)
    CE(0,2) CE(1,3) CE(4,6) CE(5,7)
    CE(1,2) CE(5,6) CE(0,4) CE(3,7)
    CE(1,5) CE(2,6)
    CE(1,4) CE(3,6)
    CE(2,4) CE(3,5)
    CE(3,4)
#undef CE

    float prevc = 0.f;
#pragma unroll
    for (int j = 0; j < 9; j++) {
        float cj = (j < 8) ? c[j] : 1.0f;
        uint32_t h = 0;
        int prev = 0;
#pragma unroll
        for (int i2 = 0; i2 < 8; i2++) {
            int ai = base[i2] + (fr[i2] >= cj ? 1 : 0);
            h ^= (uint32_t)(ai - prev) * PR[i2];
            prev = ai;
        }
        idx9[j] = h & (TBL - 1);
        w9[j]   = cj - prevc;
        prevc   = cj;
    }
}

// ---------------- encoding: level-major, asm-batched gathers ----------------
__global__ __launch_bounds__(256) void k_encode(
    const float* __restrict__ x, const float* __restrict__ T,
    const float* __restrict__ Karr, unsigned short* __restrict__ h0T)
{
    int i = blockIdx.x;
    int l = (i & 7) + ((i >> 10) << 3);
    int b = ((i & 1023) >> 3) * 256 + threadIdx.x;

    const float4 x0 = *(const float4*)(x + (size_t)b * DD);
    const float4 x1 = *(const float4*)(x + (size_t)b * DD + 4);
    float xs[8] = {x0.x, x0.y, x0.z, x0.w, x1.x, x1.y, x1.z, x1.w};

    float Kl = Karr[l];
    const f32x2* Tl = (const f32x2*)(T + ((size_t)l * TBL) * 2);

    uint32_t idx9[9];
    float    w9[9];
    enc_idx(xs, Kl, idx9, w9);

    f32x2 t0, t1, t2, t3, t4, t5, t6, t7, t8;
#define GL(n) asm volatile("global_load_dwordx2 %0, %1, off" \
                           : "=v"(t##n) : "v"(Tl + idx9[n]));
    GL(0) GL(1) GL(2) GL(3) GL(4) GL(5) GL(6) GL(7) GL(8)
#undef GL
    asm volatile("s_waitcnt vmcnt(0)"
        : "+v"(t0), "+v"(t1), "+v"(t2), "+v"(t3), "+v"(t4),
          "+v"(t5), "+v"(t6), "+v"(t7), "+v"(t8));
    __builtin_amdgcn_sched_barrier(0);

    float f0, f1;
    f0 = t0[0] * w9[0];  f1 = t0[1] * w9[0];
    f0 = fmaf(t1[0], w9[1], f0); f1 = fmaf(t1[1], w9[1], f1);
    f0 = fmaf(t2[0], w9[2], f0); f1 = fmaf(t2[1], w9[2], f1);
    f0 = fmaf(t3[0], w9[3], f0); f1 = fmaf(t3[1], w9[3], f1);
    f0 = fmaf(t4[0], w9[4], f0); f1 = fmaf(t4[1], w9[4], f1);
    f0 = fmaf(t5[0], w9[5], f0); f1 = fmaf(t5[1], w9[5], f1);
    f0 = fmaf(t6[0], w9[6], f0); f1 = fmaf(t6[1], w9[6], f1);
    f0 = fmaf(t7[0], w9[7], f0); f1 = fmaf(t7[1], w9[7], f1);
    f0 = fmaf(t8[0], w9[8], f0); f1 = fmaf(t8[1], w9[8], f1);
    f0 /= Kl;
    f1 /= Kl;

    h0T[(size_t)(l * 2 + 0) * BB + b] = f2bf(f0);
    h0T[(size_t)(l * 2 + 1) * BB + b] = f2bf(f1);
}

// ---------------- pack: planes + x -> row-major bf16 [B][64] (zero-padded K) ----
__global__ __launch_bounds__(256) void k_pack(
    const unsigned short* __restrict__ h0T, const float* __restrict__ x,
    unsigned short* __restrict__ h0b)
{
    int b = blockIdx.x * 256 + threadIdx.x;
    unsigned short row[64];
    const float4 x0 = *(const float4*)(x + (size_t)b * 8);
    const float4 x1 = *(const float4*)(x + (size_t)b * 8 + 4);
    row[0] = f2bf(x0.x); row[1] = f2bf(x0.y); row[2] = f2bf(x0.z); row[3] = f2bf(x0.w);
    row[4] = f2bf(x1.x); row[5] = f2bf(x1.y); row[6] = f2bf(x1.z); row[7] = f2bf(x1.w);
#pragma unroll
    for (int p = 0; p < 32; p++) row[8 + p] = h0T[(size_t)p * BB + b];
#pragma unroll
    for (int c = 40; c < 64; c++) row[c] = 0;
#pragma unroll
    for (int i = 0; i < 8; i++)
        *(u16x8*)(h0b + (size_t)b * 64 + i * 8) = *(u16x8*)(row + i * 8);
}

// ---------------- fused weight converts: w2 (256 blocks) + w1-pad (32 blocks) ----
__global__ __launch_bounds__(256) void k_cvtw(
    const float* __restrict__ w2, unsigned short* __restrict__ o2,
    const float* __restrict__ w1, unsigned short* __restrict__ o1)
{
    int bid = blockIdx.x;
    if (bid < 256) {
        int i = bid * 256 + threadIdx.x;
        float4 v = *(const float4*)(w2 + (size_t)i * 4);
        ushort4 r;
        r.x = f2bf(v.x); r.y = f2bf(v.y); r.z = f2bf(v.z); r.w = f2bf(v.w);
        *(ushort4*)(o2 + (size_t)i * 4) = r;
    } else {
        int i = (bid - 256) * 256 + threadIdx.x;   // 8192 threads
        int row = i >> 4, c4 = (i & 15) * 4;
        ushort4 r = make_ushort4(0, 0, 0, 0);
        if (c4 < 40) {
            float4 v = *(const float4*)(w1 + (size_t)row * 40 + c4);
            r.x = f2bf(v.x); r.y = f2bf(v.y); r.z = f2bf(v.z); r.w = f2bf(v.w);
        }
        *(ushort4*)(o1 + (size_t)row * 64 + c4) = r;
    }
}

// ---------------- fused MLP: h0b -> (gemm1 -> h1 in LDS -> gemm2 -> heads) ----------------
// 256 blocks x 512 threads (8 waves: wm=wid>>2 row-half, wn=wid&3 col-quarter).
// Block owns 128 samples. h1 tile (128x512 bf16, XOR-swizzled) never leaves LDS.
// B-operands (w1b, w2b) are loaded as contiguous 16B fragments straight from
// global: identical addresses across all blocks -> L2-resident after first touch.
__global__ __launch_bounds__(512) void k_fused(
    const unsigned short* __restrict__ h0b, const unsigned short* __restrict__ w1b,
    const unsigned short* __restrict__ w2b, const float* __restrict__ b1,
    const float* __restrict__ b2, const float* __restrict__ aw,
    const float* __restrict__ vw, float* __restrict__ hpart)
{
    __shared__ unsigned short h1s[128 * 512];   // 128 KiB, swizzled [row][k]
    __shared__ unsigned short h0s[128 * 64];    // 16 KiB,  swizzled [row][k]

    const int tid  = threadIdx.x;
    const int wid  = tid >> 6;
    const int lane = tid & 63;
    const int wm = wid >> 2, wn = wid & 3;
    const int lr = lane & 15;
    const int kg = lane >> 4;
    const int b0 = blockIdx.x * 128;

    // ---- stage h0 tile: 16 KB, inverse-swizzled source, linear LDS dest ----
#pragma unroll
    for (int it = 0; it < 2; ++it) {
        int offb  = (it * 512 + tid) << 4;
        int loffb = offb ^ (((offb >> 7) & 7) << 4);
        int row = loffb >> 7;            // 0..127
        int kel = (loffb & 127) >> 1;    // element offset, multiple of 8
        int ldsbyte = ((it * 512) + (wid * 64)) << 4;
        gload_lds16(h0b + (size_t)(b0 + row) * 64 + kel, (char*)h0s + ldsbyte);
    }
    __syncthreads();

    f32x4 acc[4][8];
#pragma unroll
    for (int m = 0; m < 4; ++m)
#pragma unroll
        for (int n = 0; n < 8; ++n) acc[m][n] = (f32x4){0.f, 0.f, 0.f, 0.f};

    // ---- phase 1: h1 = relu(h0 @ w1^T + b1), K=64 ----
#pragma unroll
    for (int ks = 0; ks < 2; ++ks) {
        int kbyte = ks * 64 + kg * 16;
        short8 af[4];
#pragma unroll
        for (int m = 0; m < 4; ++m) {
            int row = wm * 64 + m * 16 + lr;
            int a = ((row << 7) + kbyte) ^ ((row & 7) << 4);
            af[m] = *(const short8*)((const char*)h0s + a);
        }
        short8 bfr[8];
#pragma unroll
        for (int n = 0; n < 8; ++n) {
            int col = wn * 128 + n * 16 + lr;
            bfr[n] = *(const short8*)(w1b + (size_t)col * 64 + ks * 32 + kg * 8);
        }
#pragma unroll
        for (int m = 0; m < 4; ++m)
#pragma unroll
            for (int n = 0; n < 8; ++n)
                acc[m][n] = __builtin_amdgcn_mfma_f32_16x16x32_bf16(
                    af[m], bfr[n], acc[m][n], 0, 0, 0);
    }

    // bias + relu -> bf16 -> swizzled LDS h1 tile (row stride 1024 B)
#pragma unroll
    for (int n = 0; n < 8; ++n) {
        int col = wn * 128 + n * 16 + lr;
        float b1v = b1[col];
#pragma unroll
        for (int m = 0; m < 4; ++m) {
            int rbase = wm * 64 + m * 16 + kg * 4;
#pragma unroll
            for (int r = 0; r < 4; ++r) {
                int row = rbase + r;
                int byte = ((row << 10) + col * 2) ^ ((row & 7) << 4);
                *(unsigned short*)((char*)h1s + byte) =
                    f2bf(fmaxf(acc[m][n][r] + b1v, 0.f));
            }
        }
    }
    __syncthreads();    // ds_writes drained (lgkmcnt) + all waves done

    // ---- phase 2: h2 = relu(h1 @ w2^T + b2), K=512, A from LDS, B from L2 ----
#pragma unroll
    for (int m = 0; m < 4; ++m)
#pragma unroll
        for (int n = 0; n < 8; ++n) acc[m][n] = (f32x4){0.f, 0.f, 0.f, 0.f};

    for (int kc = 0; kc < 16; ++kc) {
        int kbyte = kc * 64 + kg * 16;
        short8 af[4];
#pragma unroll
        for (int m = 0; m < 4; ++m) {
            int row = wm * 64 + m * 16 + lr;
            int a = ((row << 10) + kbyte) ^ ((row & 7) << 4);
            af[m] = *(const short8*)((const char*)h1s + a);
        }
        short8 bfr[8];
#pragma unroll
        for (int n = 0; n < 8; ++n) {
            int col = wn * 128 + n * 16 + lr;
            bfr[n] = *(const short8*)(w2b + (size_t)col * 512 + kc * 32 + kg * 8);
        }
#pragma unroll
        for (int m = 0; m < 4; ++m)
#pragma unroll
            for (int n = 0; n < 8; ++n)
                acc[m][n] = __builtin_amdgcn_mfma_f32_16x16x32_bf16(
                    af[m], bfr[n], acc[m][n], 0, 0, 0);
    }

    // ---- fused heads epilogue: bias+relu (fp32), dot with head weights ----
#pragma unroll
    for (int n = 0; n < 8; ++n) {
        int col = wn * 128 + n * 16 + lr;
        float b2v = b2[col];
#pragma unroll
        for (int m = 0; m < 4; ++m)
#pragma unroll
            for (int r = 0; r < 4; ++r)
                acc[m][n][r] = fmaxf(acc[m][n][r] + b2v, 0.f);
    }

    float hwv[5][8];
#pragma unroll
    for (int n = 0; n < 8; ++n) {
        int col = wn * 128 + n * 16 + lr;
        hwv[0][n] = aw[col];
        hwv[1][n] = aw[512 + col];
        hwv[2][n] = aw[1024 + col];
        hwv[3][n] = aw[1536 + col];
        hwv[4][n] = vw[col];
    }
    float* hp = hpart + (size_t)wn * (BB * 5);
#pragma unroll
    for (int hm = 0; hm < 5; ++hm) {
        f32x4 p[4];
#pragma unroll
        for (int m = 0; m < 4; ++m) {
            p[m] = acc[m][0] * hwv[hm][0];
#pragma unroll
            for (int n = 1; n < 8; ++n) p[m] += acc[m][n] * hwv[hm][n];
        }
#pragma unroll
        for (int d = 1; d < 16; d <<= 1)
#pragma unroll
            for (int m = 0; m < 4; ++m)
#pragma unroll
                for (int r = 0; r < 4; ++r)
                    p[m][r] += __shfl_xor(p[m][r], d);
        if (lr == 0) {
#pragma unroll
            for (int m = 0; m < 4; ++m)
#pragma unroll
                for (int r = 0; r < 4; ++r)
                    hp[(size_t)(b0 + wm * 64 + m * 16 + kg * 4 + r) * 5 + hm] = p[m][r];
        }
    }
}

// ---------------- reduce 4 head-partial slots + bias -> out ----------------
__global__ __launch_bounds__(256) void k_hreduce(
    const float* __restrict__ hpart, const float* __restrict__ ab,
    const float* __restrict__ vb, float* __restrict__ out)
{
    int i = blockIdx.x * 256 + threadIdx.x;    // 0 .. BB*5-1, = b*5+hm
    int b = i / 5;
    int hm = i - b * 5;
    float s = 0.f;
#pragma unroll
    for (int g = 0; g < 4; ++g) s += hpart[(size_t)g * (BB * 5) + i];
    s += (hm < 4) ? ab[hm] : vb[0];
    if (hm < 4) out[(size_t)b * 4 + hm] = s;
    else        out[(size_t)BB * 4 + b] = s;
}

extern "C" void kernel_launch(void* const* d_in, const int* in_sizes, int n_in,
                              void* d_out, int out_size, void* d_ws, size_t ws_size,
                              hipStream_t stream)
{
    const float* x    = (const float*)d_in[0];
    const float* T    = (const float*)d_in[1];
    const float* K    = (const float*)d_in[2];
    const float* l1w  = (const float*)d_in[3];
    const float* l1b  = (const float*)d_in[4];
    const float* l2w  = (const float*)d_in[5];
    const float* l2b  = (const float*)d_in[6];
    const float* actw = (const float*)d_in[7];
    const float* actb = (const float*)d_in[8];
    const float* valw = (const float*)d_in[9];
    const float* valb = (const float*)d_in[10];
    float* out = (float*)d_out;

    char* ws = (char*)d_ws;
    unsigned short* h0b   = (unsigned short*)ws;                  // B*64 bf16   = 4,194,304 B
    unsigned short* h0T   = (unsigned short*)(ws + 4194304);      // 32*B bf16   = 2,097,152 B
    unsigned short* w2b   = (unsigned short*)(ws + 6291456);      // 512*512 bf16= 524,288 B
    unsigned short* w1b   = (unsigned short*)(ws + 6815744);      // 512*64 bf16 = 65,536 B
    float*          hpart = (float*)(ws + 6881280);               // 4*B*5 f32   = 2,621,440 B

    k_encode  <<<2048, 256, 0, stream>>>(x, T, K, h0T);
    k_cvtw    <<<288, 256, 0, stream>>>(l2w, w2b, l1w, w1b);
    k_pack    <<<BB / 256, 256, 0, stream>>>(h0T, x, h0b);
    k_fused   <<<256, 512, 0, stream>>>(h0b, w1b, w2b, l1b, l2b, actw, valw, hpart);
    k_hreduce <<<BB * 5 / 256, 256, 0, stream>>>(hpart, actb, valb, out);
}